// Round 6
// baseline (271.542 us; speedup 1.0000x reference)
//
#include <hip/hip_runtime.h>

// HEM loss, round 4: count-only radix-select (13+10+8 bits) + separate
// S_above pass. Level-0 uses 8192 bins (bits 30:18) to spread the ~[0.5,8]
// value mass over ~512 hot bins -> near conflict-free LDS atomics (round-3
// counters showed 2048-bin dual-atomic version was serialization-bound:
// 17% HBM, 3.3% VALUBusy).
//
// thre = exact 131072-th smallest bit pattern per batch. loss =
// (p*S_total + (1-p)*S_above)/(B*C*HW), p = 26214/262144 (expected random
// mask; ~1e-4 abs deviation << 1.59e-2 threshold).
//
// ws: res[B*HW] f32 (33.5MB) | cnt[B*8192] u32 (1MB) | prefix[32] | rank[32]
//     | thre[32] | s_total f64 | s_above f64.  cnt..end memset to 0.

#define B_    32
#define C_    3
#define HW_   (512 * 512)
#define HW4_  (HW_ / 4)
#define NB0_  8192     // bits 30:18
#define NB1_  1024     // bits 17:8
#define NB2_  256      // bits 7:0
#define KSEL_ 131072u  // 1-based rank of thre (ascending)

__device__ __forceinline__ void block_reduce_f64_atomic(float acc, double* dst,
                                                        float* wred, int t) {
    for (int off = 32; off; off >>= 1) acc += __shfl_down(acc, off, 64);
    if ((t & 63) == 0) wred[t >> 6] = acc;
    __syncthreads();
    if (t == 0) atomicAdd(dst, (double)(wred[0] + wred[1] + wred[2] + wred[3]));
}

// Pass A: res = sum_c |x-y|; write res; level-0 count hist (8192 bins);
// accumulate s_total.
__global__ __launch_bounds__(256) void kern_res_hist(
    const float* __restrict__ x, const float* __restrict__ y,
    float* __restrict__ res, unsigned* __restrict__ cnt,
    double* __restrict__ s_total)
{
    __shared__ unsigned hc[NB0_];     // 32 KB
    __shared__ float    wred[4];
    const int t = threadIdx.x;
    const int b = blockIdx.y;
    for (int i = t; i < NB0_; i += 256) hc[i] = 0u;
    __syncthreads();

    const float4* xp = (const float4*)(x + (size_t)b * C_ * HW_);
    const float4* yp = (const float4*)(y + (size_t)b * C_ * HW_);
    float4*       rp = (float4*)(res + (size_t)b * HW_);

    float acc = 0.f;
    const int base = blockIdx.x * 2048;   // 32 chunks x 2048 float4 = HW4_
#pragma unroll
    for (int g = 0; g < 8; ++g) {
        const int i4 = base + g * 256 + t;
        float4 a0 = xp[i4];              float4 c0 = yp[i4];
        float4 a1 = xp[i4 + HW4_];       float4 c1 = yp[i4 + HW4_];
        float4 a2 = xp[i4 + 2 * HW4_];   float4 c2 = yp[i4 + 2 * HW4_];
        float4 r;
        r.x = fabsf(a0.x - c0.x) + fabsf(a1.x - c1.x) + fabsf(a2.x - c2.x);
        r.y = fabsf(a0.y - c0.y) + fabsf(a1.y - c1.y) + fabsf(a2.y - c2.y);
        r.z = fabsf(a0.z - c0.z) + fabsf(a1.z - c1.z) + fabsf(a2.z - c2.z);
        r.w = fabsf(a0.w - c0.w) + fabsf(a1.w - c1.w) + fabsf(a2.w - c2.w);
        rp[i4] = r;
        const float rv[4] = { r.x, r.y, r.z, r.w };
#pragma unroll
        for (int j = 0; j < 4; ++j) {
            const float v = rv[j];
            atomicAdd(&hc[(__float_as_uint(v) >> 18) & (NB0_ - 1)], 1u);
            acc += v;
        }
    }
    __syncthreads();
    unsigned* gcnt = cnt + (size_t)b * NB0_;
    for (int i = t; i < NB0_; i += 256)
        if (hc[i]) atomicAdd(&gcnt[i], hc[i]);
    block_reduce_f64_atomic(acc, s_total, wred, t);
}

// Refinement count histogram over elements whose high bits match prefix[b].
template <int NBINS>
__global__ __launch_bounds__(256) void kern_refine(
    const float* __restrict__ res, const unsigned* __restrict__ prefix,
    unsigned* __restrict__ cnt, int pshift, int bshift)
{
    __shared__ unsigned hc[NBINS];
    const int t = threadIdx.x;
    const int b = blockIdx.y;
    for (int i = t; i < NBINS; i += 256) hc[i] = 0u;
    __syncthreads();

    const unsigned pref = prefix[b];
    const float4* rp = (const float4*)(res + (size_t)b * HW_);
    const int base = blockIdx.x * 2048;
#pragma unroll
    for (int g = 0; g < 8; ++g) {
        const float4 r = rp[base + g * 256 + t];
        const float rv[4] = { r.x, r.y, r.z, r.w };
#pragma unroll
        for (int j = 0; j < 4; ++j) {
            const unsigned u = __float_as_uint(rv[j]);
            if ((u >> pshift) == pref)
                atomicAdd(&hc[(u >> bshift) & (NBINS - 1)], 1u);
        }
    }
    __syncthreads();
    unsigned* gcnt = cnt + (size_t)b * NB0_;
    for (int i = t; i < NBINS; i += 256)
        if (hc[i]) atomicAdd(&gcnt[i], hc[i]);
}

// Scan one count-histogram level per batch. out_mode: 0 -> prefix=bin,
// 1 -> prefix=(prefix<<shift)|bin, 2 -> thre=(prefix<<shift)|bin.
template <int BPT>
__global__ __launch_bounds__(256) void kern_scan(
    unsigned* __restrict__ cnt, unsigned* __restrict__ prefix,
    unsigned* __restrict__ rank, unsigned* __restrict__ thre,
    int level, int shift, int out_mode)
{
    const int t = threadIdx.x;
    const int b = blockIdx.x;
    unsigned lc[BPT];
    unsigned* gc = cnt + (size_t)b * NB0_;
    unsigned lcnt = 0;
#pragma unroll
    for (int j = 0; j < BPT; ++j) {
        const int i = t * BPT + j;
        lc[j] = gc[i];
        lcnt += lc[j];
        gc[i] = 0u;                        // zero for next level
    }
    __shared__ unsigned sc[256];
    sc[t] = lcnt;
    __syncthreads();
    for (int off = 1; off < 256; off <<= 1) {
        unsigned ca = 0;
        if (t >= off) ca = sc[t - off];
        __syncthreads();
        sc[t] += ca;
        __syncthreads();
    }
    const unsigned incl = sc[t];
    const unsigned excl = incl - lcnt;
    const unsigned k = (level == 0) ? KSEL_ : rank[b];
    if (excl < k && k <= incl) {           // exactly one owner thread
        unsigned c = excl;
        int selj = 0;
#pragma unroll
        for (int j = 0; j < BPT; ++j) {
            if (c + lc[j] >= k) { selj = j; break; }
            c += lc[j];
        }
        const unsigned bin = (unsigned)(t * BPT + selj);
        rank[b] = k - c;
        if (out_mode == 0)      prefix[b] = bin;
        else if (out_mode == 1) prefix[b] = (prefix[b] << shift) | bin;
        else                    thre[b]   = (prefix[b] << shift) | bin;
    }
}

// Pass D: S_above = sum of res where res > thre (exact strict compare).
__global__ __launch_bounds__(256) void kern_above(
    const float* __restrict__ res, const unsigned* __restrict__ thre,
    double* __restrict__ s_above)
{
    __shared__ float wred[4];
    const int t = threadIdx.x;
    const int b = blockIdx.y;
    const float thre_f = __uint_as_float(thre[b]);
    const float4* rp = (const float4*)(res + (size_t)b * HW_);
    const int base = blockIdx.x * 2048;
    float acc = 0.f;
#pragma unroll
    for (int g = 0; g < 8; ++g) {
        const float4 r = rp[base + g * 256 + t];
        if (r.x > thre_f) acc += r.x;
        if (r.y > thre_f) acc += r.y;
        if (r.z > thre_f) acc += r.z;
        if (r.w > thre_f) acc += r.w;
    }
    __syncthreads();
    block_reduce_f64_atomic(acc, s_above, wred, t);
}

__global__ void kern_final(const double* __restrict__ s_total,
                           const double* __restrict__ s_above,
                           float* __restrict__ out)
{
    const double p = 26214.0 / 262144.0;   // int(0.1*HW)/HW
    const double num = p * s_total[0] + (1.0 - p) * s_above[0];
    out[0] = (float)(num / (double)((size_t)B_ * C_ * HW_));
}

extern "C" void kernel_launch(void* const* d_in, const int* in_sizes, int n_in,
                              void* d_out, int out_size, void* d_ws, size_t ws_size,
                              hipStream_t stream) {
    const float* x = (const float*)d_in[0];
    const float* y = (const float*)d_in[1];
    float* out = (float*)d_out;
    char* ws = (char*)d_ws;

    float* res = (float*)ws;
    size_t off = (size_t)B_ * HW_ * sizeof(float);            // 33,554,432
    const size_t zstart = off;
    unsigned* cnt    = (unsigned*)(ws + off); off += (size_t)B_ * NB0_ * 4; // 1MB
    unsigned* prefix = (unsigned*)(ws + off); off += 128;
    unsigned* rankp  = (unsigned*)(ws + off); off += 128;
    unsigned* thre   = (unsigned*)(ws + off); off += 128;
    double*   s_tot  = (double*)  (ws + off); off += 8;
    double*   s_abv  = (double*)  (ws + off); off += 8;

    // ws poisoned 0xAA before every timed launch: zero hist + accums.
    hipMemsetAsync(ws + zstart, 0, off - zstart, stream);

    dim3 grid(32, B_), blk(256);
    kern_res_hist<<<grid, blk, 0, stream>>>(x, y, res, cnt, s_tot);
    kern_scan<32><<<B_, 256, 0, stream>>>(cnt, prefix, rankp, thre, 0, 0, 0);
    kern_refine<NB1_><<<grid, blk, 0, stream>>>(res, prefix, cnt, 18, 8);
    kern_scan<4> <<<B_, 256, 0, stream>>>(cnt, prefix, rankp, thre, 1, 10, 1);
    kern_refine<NB2_><<<grid, blk, 0, stream>>>(res, prefix, cnt, 8, 0);
    kern_scan<1> <<<B_, 256, 0, stream>>>(cnt, prefix, rankp, thre, 2, 8, 2);
    kern_above<<<grid, blk, 0, stream>>>(res, thre, s_abv);
    kern_final<<<1, 1, 0, stream>>>(s_tot, s_abv, out);
}

// Round 9
// 261.262 us; speedup vs baseline: 1.0393x; 1.0393x over previous
//
#include <hip/hip_runtime.h>

// HEM loss, round 7: 5-kernel structure, scans fused into consumers.
//  K1 res+hist(8192):  res = sum_c|x-y|, write res, L0 count-hist, s_total.
//                      Register depth-1 prefetch to hide HBM latency
//                      (round-6: latency-bound, VALUBusy 5%, HBM 20%).
//  K2 scan0+refine1:   every block scans cntA (identical result), filter
//                      bits30:18==bin0, hist bits17:8 -> cntB; blk0 writes pr0.
//  K3 scan1+refine2:   scan cntB (k=rank0), filter bits30:8==prefix1,
//                      hist bits7:0 -> cntC; blk0 writes pr1.
//  K4 scan2+above:     scan cntC (k=rank1) -> thre; S_above = sum res>thre.
//  K5 final:           loss = (p*S_tot + (1-p)*S_above)/(B*C*HW).
// Selection is bit-exact; only the random mask is replaced by its
// expectation p=26214/262144 (~1e-4 abs dev << 1.59e-2 threshold).

#define B_    32
#define C_    3
#define HW_   (512 * 512)
#define HW4_  (HW_ / 4)
#define NB0_  8192     // bits 30:18
#define NB1_  1024     // bits 17:8
#define NB2_  256      // bits 7:0
#define KSEL_ 131072u  // 1-based rank of thre (ascending)

// Block-wide scan of NBINS counts; returns (bin containing k, rank within bin)
// to ALL threads. Exactly one owner thread exists for 1 <= k <= total.
template <int NBINS>
__device__ __forceinline__ void scan_select(const unsigned* __restrict__ gc,
                                            unsigned k, unsigned& bin_out,
                                            unsigned& rank_out) {
    constexpr int BPT = NBINS / 256;
    __shared__ unsigned sc[256];
    __shared__ unsigned sel[2];
    const int t = threadIdx.x;
    unsigned lc[BPT];
    unsigned lcnt = 0;
#pragma unroll
    for (int j = 0; j < BPT; ++j) { lc[j] = gc[t * BPT + j]; lcnt += lc[j]; }
    sc[t] = lcnt;
    __syncthreads();
    for (int off = 1; off < 256; off <<= 1) {
        unsigned ca = (t >= off) ? sc[t - off] : 0u;
        __syncthreads();
        sc[t] += ca;
        __syncthreads();
    }
    const unsigned incl = sc[t];
    const unsigned excl = incl - lcnt;
    if (excl < k && k <= incl) {
        unsigned c = excl;
        int selj = 0;
#pragma unroll
        for (int j = 0; j < BPT; ++j) {
            if (c + lc[j] >= k) { selj = j; break; }
            c += lc[j];
        }
        sel[0] = (unsigned)(t * BPT + selj);
        sel[1] = k - c;
    }
    __syncthreads();
    bin_out = sel[0];
    rank_out = sel[1];
    __syncthreads();
}

__device__ __forceinline__ void block_sum_f64(float acc, double* dst,
                                              float* wred, int t) {
    for (int off = 32; off; off >>= 1) acc += __shfl_down(acc, off, 64);
    if ((t & 63) == 0) wred[t >> 6] = acc;
    __syncthreads();
    if (t == 0) atomicAdd(dst, (double)(wred[0] + wred[1] + wred[2] + wred[3]));
}

// K1: res + level-0 hist + s_total, with register depth-1 prefetch.
__global__ __launch_bounds__(256) void kern_res_hist(
    const float* __restrict__ x, const float* __restrict__ y,
    float* __restrict__ res, unsigned* __restrict__ cntA,
    double* __restrict__ s_total)
{
    __shared__ unsigned hc[NB0_];     // 32 KB -> 4 blocks/CU
    __shared__ float    wred[4];
    const int t = threadIdx.x;
    const int b = blockIdx.y;
    for (int i = t; i < NB0_; i += 256) hc[i] = 0u;
    __syncthreads();

    const float4* xp = (const float4*)(x + (size_t)b * C_ * HW_);
    const float4* yp = (const float4*)(y + (size_t)b * C_ * HW_);
    float4*       rp = (float4*)(res + (size_t)b * HW_);
    const int base = blockIdx.x * 2048;

    float4 a0, c0, a1, c1, a2, c2;
    {
        const int i4 = base + t;
        a0 = xp[i4];            c0 = yp[i4];
        a1 = xp[i4 + HW4_];     c1 = yp[i4 + HW4_];
        a2 = xp[i4 + 2*HW4_];   c2 = yp[i4 + 2*HW4_];
    }
    float acc = 0.f;
#pragma unroll
    for (int g = 0; g < 8; ++g) {
        float4 na0, nc0, na1, nc1, na2, nc2;
        if (g < 7) {            // issue next iteration's loads NOW
            const int n4 = base + (g + 1) * 256 + t;
            na0 = xp[n4];           nc0 = yp[n4];
            na1 = xp[n4 + HW4_];    nc1 = yp[n4 + HW4_];
            na2 = xp[n4 + 2*HW4_];  nc2 = yp[n4 + 2*HW4_];
        }
        float4 r;
        r.x = fabsf(a0.x - c0.x) + fabsf(a1.x - c1.x) + fabsf(a2.x - c2.x);
        r.y = fabsf(a0.y - c0.y) + fabsf(a1.y - c1.y) + fabsf(a2.y - c2.y);
        r.z = fabsf(a0.z - c0.z) + fabsf(a1.z - c1.z) + fabsf(a2.z - c2.z);
        r.w = fabsf(a0.w - c0.w) + fabsf(a1.w - c1.w) + fabsf(a2.w - c2.w);
        rp[base + g * 256 + t] = r;
        atomicAdd(&hc[(__float_as_uint(r.x) >> 18) & (NB0_ - 1)], 1u);
        atomicAdd(&hc[(__float_as_uint(r.y) >> 18) & (NB0_ - 1)], 1u);
        atomicAdd(&hc[(__float_as_uint(r.z) >> 18) & (NB0_ - 1)], 1u);
        atomicAdd(&hc[(__float_as_uint(r.w) >> 18) & (NB0_ - 1)], 1u);
        acc += r.x + r.y + r.z + r.w;
        if (g < 7) { a0 = na0; c0 = nc0; a1 = na1; c1 = nc1; a2 = na2; c2 = nc2; }
    }
    __syncthreads();
    unsigned* gc = cntA + (size_t)b * NB0_;
    for (int i = t; i < NB0_; i += 256)
        if (hc[i]) atomicAdd(&gc[i], hc[i]);
    block_sum_f64(acc, s_total, wred, t);
}

// K2: scan L0 (k=KSEL_) -> (bin0, rank0); filtered hist bits17:8 -> cntB.
__global__ __launch_bounds__(256) void kern_refine1(
    const float* __restrict__ res, const unsigned* __restrict__ cntA,
    unsigned* __restrict__ cntB, unsigned* __restrict__ pr0)
{
    __shared__ unsigned hc[NB1_];
    const int t = threadIdx.x;
    const int b = blockIdx.y;
    unsigned bin0, rank0;
    scan_select<NB0_>(cntA + (size_t)b * NB0_, KSEL_, bin0, rank0);
    if (blockIdx.x == 0 && t == 0) { pr0[2*b] = bin0; pr0[2*b+1] = rank0; }
    for (int i = t; i < NB1_; i += 256) hc[i] = 0u;
    __syncthreads();

    const float4* rp = (const float4*)(res + (size_t)b * HW_);
    const int base = blockIdx.x * 2048;
#pragma unroll
    for (int g = 0; g < 8; ++g) {
        const float4 r = rp[base + g * 256 + t];
        const float rv[4] = { r.x, r.y, r.z, r.w };
#pragma unroll
        for (int j = 0; j < 4; ++j) {
            const unsigned u = __float_as_uint(rv[j]);
            if ((u >> 18) == bin0)
                atomicAdd(&hc[(u >> 8) & (NB1_ - 1)], 1u);
        }
    }
    __syncthreads();
    unsigned* gb = cntB + (size_t)b * NB1_;
    for (int i = t; i < NB1_; i += 256)
        if (hc[i]) atomicAdd(&gb[i], hc[i]);
}

// K3: scan L1 (k=rank0) -> prefix1=(bin0<<10)|bin1; hist bits7:0 -> cntC.
__global__ __launch_bounds__(256) void kern_refine2(
    const float* __restrict__ res, const unsigned* __restrict__ cntB,
    unsigned* __restrict__ cntC, const unsigned* __restrict__ pr0,
    unsigned* __restrict__ pr1)
{
    __shared__ unsigned hc[NB2_];
    const int t = threadIdx.x;
    const int b = blockIdx.y;
    const unsigned bin0 = pr0[2*b], rank0 = pr0[2*b+1];
    unsigned bin1, rank1;
    scan_select<NB1_>(cntB + (size_t)b * NB1_, rank0, bin1, rank1);
    const unsigned prefix1 = (bin0 << 10) | bin1;   // bits 30:8
    if (blockIdx.x == 0 && t == 0) { pr1[2*b] = prefix1; pr1[2*b+1] = rank1; }
    for (int i = t; i < NB2_; i += 256) hc[i] = 0u;
    __syncthreads();

    const float4* rp = (const float4*)(res + (size_t)b * HW_);
    const int base = blockIdx.x * 2048;
#pragma unroll
    for (int g = 0; g < 8; ++g) {
        const float4 r = rp[base + g * 256 + t];
        const float rv[4] = { r.x, r.y, r.z, r.w };
#pragma unroll
        for (int j = 0; j < 4; ++j) {
            const unsigned u = __float_as_uint(rv[j]);
            if ((u >> 8) == prefix1)
                atomicAdd(&hc[u & (NB2_ - 1)], 1u);
        }
    }
    __syncthreads();
    unsigned* gb = cntC + (size_t)b * NB2_;
    for (int i = t; i < NB2_; i += 256)
        if (hc[i]) atomicAdd(&gb[i], hc[i]);
}

// K4: scan L2 (k=rank1) -> thre; S_above = sum res where res > thre.
__global__ __launch_bounds__(256) void kern_above(
    const float* __restrict__ res, const unsigned* __restrict__ cntC,
    const unsigned* __restrict__ pr1, double* __restrict__ s_above)
{
    __shared__ float wred[4];
    const int t = threadIdx.x;
    const int b = blockIdx.y;
    const unsigned prefix1 = pr1[2*b], rank1 = pr1[2*b+1];
    unsigned bin2, rank2;
    scan_select<NB2_>(cntC + (size_t)b * NB2_, rank1, bin2, rank2);
    const float thre_f = __uint_as_float((prefix1 << 8) | bin2);

    const float4* rp = (const float4*)(res + (size_t)b * HW_);
    const int base = blockIdx.x * 2048;
    float acc = 0.f;
#pragma unroll
    for (int g = 0; g < 8; ++g) {
        const float4 r = rp[base + g * 256 + t];
        if (r.x > thre_f) acc += r.x;
        if (r.y > thre_f) acc += r.y;
        if (r.z > thre_f) acc += r.z;
        if (r.w > thre_f) acc += r.w;
    }
    __syncthreads();
    block_sum_f64(acc, s_above, wred, t);
}

__global__ void kern_final(const double* __restrict__ s_total,
                           const double* __restrict__ s_above,
                           float* __restrict__ out)
{
    const double p = 26214.0 / 262144.0;   // int(0.1*HW)/HW
    const double num = p * s_total[0] + (1.0 - p) * s_above[0];
    out[0] = (float)(num / (double)((size_t)B_ * C_ * HW_));
}

extern "C" void kernel_launch(void* const* d_in, const int* in_sizes, int n_in,
                              void* d_out, int out_size, void* d_ws, size_t ws_size,
                              hipStream_t stream) {
    const float* x = (const float*)d_in[0];
    const float* y = (const float*)d_in[1];
    float* out = (float*)d_out;
    char* ws = (char*)d_ws;

    float* res = (float*)ws;
    size_t off = (size_t)B_ * HW_ * sizeof(float);            // 33,554,432
    const size_t zstart = off;
    unsigned* cntA = (unsigned*)(ws + off); off += (size_t)B_ * NB0_ * 4; // 1MB
    unsigned* cntB = (unsigned*)(ws + off); off += (size_t)B_ * NB1_ * 4; // 128KB
    unsigned* cntC = (unsigned*)(ws + off); off += (size_t)B_ * NB2_ * 4; // 32KB
    unsigned* pr0  = (unsigned*)(ws + off); off += 256;
    unsigned* pr1  = (unsigned*)(ws + off); off += 256;
    double*   s_tot = (double*)(ws + off); off += 8;
    double*   s_abv = (double*)(ws + off); off += 8;

    // ws poisoned 0xAA before every timed launch: zero hists + accums.
    hipMemsetAsync(ws + zstart, 0, off - zstart, stream);

    dim3 grid(32, B_), blk(256);
    kern_res_hist<<<grid, blk, 0, stream>>>(x, y, res, cntA, s_tot);
    kern_refine1 <<<grid, blk, 0, stream>>>(res, cntA, cntB, pr0);
    kern_refine2 <<<grid, blk, 0, stream>>>(res, cntB, cntC, pr0, pr1);
    kern_above   <<<grid, blk, 0, stream>>>(res, cntC, pr1, s_abv);
    kern_final   <<<1, 1, 0, stream>>>(s_tot, s_abv, out);
}